// Round 13
// baseline (261.254 us; speedup 1.0000x reference)
//
#include <hip/hip_runtime.h>
#include <hip/hip_fp16.h>
#include <math.h>

#define N_NODES 50000
#define N_EDGES 800000
#define E_TOT   850000          // edges + self loops
#define NEG_SLOPE 0.2f
#define BSTR    64              // bucket slots/node; deg=Pois(16)+1, P(deg>63)~3e-16
#define SCAT_NB ((E_TOT + 255) / 256)     // 3321 blocks: bucket-scatter part
#define GEMM_NB ((N_NODES + 15) / 16)     // 3125 blocks: gemm part

typedef unsigned short u16;     // N_NODES < 65536: src ids fit in 16b
typedef float f32x4 __attribute__((ext_vector_type(4)));  // clang vector: OK for NT builtins

// ===========================================================================
// One-pass bucket-CSR + layer-1 GEMM, fused via split grid.
// Blocks [0, SCAT_NB): for each edge, slot = atomicAdd(&deg[d],1) and
//   bucket[d*BSTR + slot] = src  (fixed stride -> no scan, no offs, no rank).
// Blocks [SCAT_NB, SCAT_NB+GEMM_NB): h = X @ W1 + attention projections.
// deg is zeroed by hipMemsetAsync before this kernel.
// ===========================================================================
__global__ void scatter_gemm(const int* __restrict__ src, const int* __restrict__ dst,
                             int* __restrict__ deg, u16* __restrict__ bucket,
                             const float* __restrict__ X, const float* __restrict__ W,
                             const float* __restrict__ a_src, const float* __restrict__ a_dst,
                             __half* __restrict__ Hh, float* __restrict__ ssrc,
                             float* __restrict__ sdst) {
    constexpr int DI = 64, DO = 64, TPN = DO / 4, NPB = 256 / TPN;
    if (blockIdx.x < SCAT_NB) {
        int e = blockIdx.x * 256 + threadIdx.x;
        if (e >= E_TOT) return;
        int s, d;
        if (e < N_EDGES) { s = src[e]; d = dst[e]; } else { s = e - N_EDGES; d = s; }
        int rk = atomicAdd(&deg[d], 1);
        bucket[d * BSTR + rk] = (u16)s;
        return;
    }
    // ---- gemm part ----
    __shared__ float sW[DI * DO];
    __shared__ float sX[NPB][DI + 1];          // +1: break broadcast bank aliasing
    const int tid = threadIdx.x;
    for (int i = tid; i < DI * DO / 4; i += 256)
        ((float4*)sW)[i] = ((const float4*)W)[i];
    const int base = (blockIdx.x - SCAT_NB) * NPB;
    for (int i = tid; i < NPB * DI; i += 256) {
        int r = i / DI, col = i % DI;
        int node = base + r;
        sX[r][col] = (node < N_NODES) ? X[(long)node * DI + col] : 0.0f;
    }
    __syncthreads();
    const int cq = tid % TPN;
    const int g  = tid / TPN;
    const int node = base + g;
    if (node >= N_NODES) return;
    float ax = 0.0f, ay = 0.0f, az = 0.0f, aw = 0.0f;
    const float4* sW4 = (const float4*)sW;
#pragma unroll
    for (int k = 0; k < DI; k++) {
        float xv = sX[g][k];
        float4 w4 = sW4[k * TPN + cq];
        ax = fmaf(xv, w4.x, ax); ay = fmaf(xv, w4.y, ay);
        az = fmaf(xv, w4.z, az); aw = fmaf(xv, w4.w, aw);
    }
    union { uint2 u; __half2 h2[2]; } pk;
    pk.h2[0] = __float22half2_rn(make_float2(ax, ay));
    pk.h2[1] = __float22half2_rn(make_float2(az, aw));
    ((uint2*)(Hh + (long)node * DO))[cq] = pk.u;

    float4 as4 = ((const float4*)a_src)[cq];
    float4 ad4 = ((const float4*)a_dst)[cq];
    float ps = ax * as4.x + ay * as4.y + az * as4.z + aw * as4.w;
    float pd = ax * ad4.x + ay * ad4.y + az * ad4.z + aw * ad4.w;
#pragma unroll
    for (int m = TPN / 2; m >= 1; m >>= 1) {
        ps += __shfl_xor(ps, m, TPN);
        pd += __shfl_xor(pd, m, TPN);
    }
    if (cq == 0) { ssrc[node] = ps; sdst[node] = pd; }
}

// ===========================================================================
// Fused: [aggregate layer i (single-pass softmax gather) + bias (+ optional
// raw output) + relu] then [next layer's GEMM + attention projections].
// Round-5 verified body; bucket CSR: beg = node*BSTR, deg from deg[].
// ===========================================================================
template<int DIN, int DOUT>
__global__ void gather_gemm(const __half* __restrict__ Hh_in,
                            const float* __restrict__ ssrc_in,
                            const float* __restrict__ sdst_in,
                            const int* __restrict__ degp,
                            const u16* __restrict__ bucket,
                            const float* __restrict__ bias_in,
                            int relu_o, float* __restrict__ extra_out,
                            const float* __restrict__ W2,
                            const float* __restrict__ a_src2,
                            const float* __restrict__ a_dst2,
                            __half* __restrict__ Hh_out,
                            float* __restrict__ ssrc2, float* __restrict__ sdst2) {
    constexpr int G = DIN / 4;                       // lanes per node group
    constexpr int L = DIN / 8;                       // lanes per row (16B each)
    constexpr int NPB = 256 / G;
    constexpr int NC = 32 / G;                       // chunks in the main path
    constexpr int JS = G / 2;                        // j-steps per chunk (2 rows/step)
    constexpr int LDSW = (DOUT > 0) ? DIN * DOUT : 1;
    __shared__ float sW[LDSW];
    if constexpr (DOUT > 0) {
        for (int i = threadIdx.x; i < DIN * DOUT / 4; i += 256)
            ((float4*)sW)[i] = ((const float4*)W2)[i];
        __syncthreads();                             // all 256 threads reach this
    }
    const int t = threadIdx.x;
    const int node = blockIdx.x * NPB + t / G;
    const int r = t % G;                             // edge slot within group
    const int hr = r / L;                            // 0/1: which edge of pair
    const int q  = r % L;                            // 16B slot within row
    const bool valid = (node < N_NODES);
    const int deg = valid ? degp[node] : 0;
    const int beg = node * BSTR;
    const int end = beg + deg;
    const float sdv = valid ? sdst_in[node] : 0.0f;
    const uint4* H4 = (const uint4*)Hh_in;

    // ---- headers for all NC main-path chunks (32 edges), issued together ----
    int   sc[NC];
    float exc[NC];
#pragma unroll
    for (int k = 0; k < NC; k++) { sc[k] = 0; exc[k] = 0.0f; }
#pragma unroll
    for (int k = 0; k < NC; k++) {
        if (k * G + r < deg) sc[k] = bucket[beg + k * G + r];
    }
#pragma unroll
    for (int k = 0; k < NC; k++) {
        if (k * G + r < deg) {
            float v = ssrc_in[sc[k]] + sdv;
            v = (v > 0.0f) ? v : NEG_SLOPE * v;
            exc[k] = __expf(v);
        }
    }
    float den = 0.0f;
#pragma unroll
    for (int k = 0; k < NC; k++) den += exc[k];

    float acc8[8];
#pragma unroll
    for (int c = 0; c < 8; c++) acc8[c] = 0.0f;

    // ---- issue ALL 16 row-loads before any FMA (branchless, masked) ----
    uint4 buf[NC * JS];
#pragma unroll
    for (int k = 0; k < NC; k++) {
#pragma unroll
        for (int j = 0; j < JS; j++) {
            int sa = __shfl(sc[k], 2 * j + hr, G);
            buf[k * JS + j] = H4[(long)sa * L + q];
        }
    }
    // ---- consume: weighted accumulate ----
#pragma unroll
    for (int k = 0; k < NC; k++) {
#pragma unroll
        for (int j = 0; j < JS; j++) {
            float ea = __shfl(exc[k], 2 * j + hr, G);
            union { uint4 u; __half2 h2[4]; } ua;
            ua.u = buf[k * JS + j];
            float2 f0 = __half22float2(ua.h2[0]), f1 = __half22float2(ua.h2[1]);
            float2 f2 = __half22float2(ua.h2[2]), f3 = __half22float2(ua.h2[3]);
            acc8[0] = fmaf(ea, f0.x, acc8[0]); acc8[1] = fmaf(ea, f0.y, acc8[1]);
            acc8[2] = fmaf(ea, f1.x, acc8[2]); acc8[3] = fmaf(ea, f1.y, acc8[3]);
            acc8[4] = fmaf(ea, f2.x, acc8[4]); acc8[5] = fmaf(ea, f2.y, acc8[5]);
            acc8[6] = fmaf(ea, f3.x, acc8[6]); acc8[7] = fmaf(ea, f3.y, acc8[7]);
        }
    }
    // ---- rare tail chunks (deg > 32; P(deg>32) small but real) ----
    for (int cb = beg + NC * G; cb < end; cb += G) {
        int cnt = min(G, end - cb);
        int s2 = 0; float ex2 = 0.0f;
        if (r < cnt) {
            s2 = bucket[cb + r];
            float v = ssrc_in[s2] + sdv;
            v = (v > 0.0f) ? v : NEG_SLOPE * v;
            ex2 = __expf(v);
        }
        den += ex2;
#pragma unroll
        for (int j = 0; j < JS; j++) {
            int   sa = __shfl(s2, 2 * j + hr, G);
            float ea = __shfl(ex2, 2 * j + hr, G);
            union { uint4 u; __half2 h2[4]; } ua;
            ua.u = H4[(long)sa * L + q];
            float2 f0 = __half22float2(ua.h2[0]), f1 = __half22float2(ua.h2[1]);
            float2 f2 = __half22float2(ua.h2[2]), f3 = __half22float2(ua.h2[3]);
            acc8[0] = fmaf(ea, f0.x, acc8[0]); acc8[1] = fmaf(ea, f0.y, acc8[1]);
            acc8[2] = fmaf(ea, f1.x, acc8[2]); acc8[3] = fmaf(ea, f1.y, acc8[3]);
            acc8[4] = fmaf(ea, f2.x, acc8[4]); acc8[5] = fmaf(ea, f2.y, acc8[5]);
            acc8[6] = fmaf(ea, f3.x, acc8[6]); acc8[7] = fmaf(ea, f3.y, acc8[7]);
        }
    }
    // merge even/odd edge halves (lanes r and r^L hold same channels)
#pragma unroll
    for (int c = 0; c < 8; c++) acc8[c] += __shfl_xor(acc8[c], L, G);
#pragma unroll
    for (int m = G / 2; m >= 1; m >>= 1) den += __shfl_xor(den, m, G);

    float inv = 1.0f / (den + 1e-16f);
    const float4* b4p = (const float4*)bias_in;
    float4 bq0 = b4p[2 * q], bq1 = b4p[2 * q + 1];
    float o8[8];
    o8[0] = acc8[0] * inv + bq0.x; o8[1] = acc8[1] * inv + bq0.y;
    o8[2] = acc8[2] * inv + bq0.z; o8[3] = acc8[3] * inv + bq0.w;
    o8[4] = acc8[4] * inv + bq1.x; o8[5] = acc8[5] * inv + bq1.y;
    o8[6] = acc8[6] * inv + bq1.z; o8[7] = acc8[7] * inv + bq1.w;
    if (valid && extra_out) {
        // hr=0 lanes store even float4 slots, hr=1 odd: contiguous 2*DIN bytes
        f32x4 st;
        if (hr == 0) { st.x = o8[0]; st.y = o8[1]; st.z = o8[2]; st.w = o8[3]; }
        else         { st.x = o8[4]; st.y = o8[5]; st.z = o8[6]; st.w = o8[7]; }
        // outputs are never re-read: non-temporal keeps H resident in L2
        __builtin_nontemporal_store(st,
            &((f32x4*)extra_out)[(long)node * (2 * L) + 2 * q + hr]);  // pre-relu
    }
    if (relu_o) {
#pragma unroll
        for (int c = 0; c < 8; c++) o8[c] = fmaxf(o8[c], 0.0f);
    }

    // ---- fused next-layer GEMM + projections ----
    if constexpr (DOUT > 0) {
        constexpr int C = DOUT / G;                  // output channels per lane
        float acc2[C];
#pragma unroll
        for (int c = 0; c < C; c++) acc2[c] = 0.0f;
        const int cbase = r * C;
#pragma unroll
        for (int kb = 0; kb < L; kb++) {             // lane kb holds chans 8kb..8kb+7
            float v[8];
#pragma unroll
            for (int c8 = 0; c8 < 8; c8++) v[c8] = __shfl(o8[c8], kb, G);
#pragma unroll
            for (int c8 = 0; c8 < 8; c8++) {
                const float* wr = &sW[(8 * kb + c8) * DOUT + cbase];
#pragma unroll
                for (int c = 0; c < C; c++) acc2[c] = fmaf(v[c8], wr[c], acc2[c]);
            }
        }
        float ps = 0.0f, pd = 0.0f;
#pragma unroll
        for (int c = 0; c < C; c++) {
            ps = fmaf(acc2[c], a_src2[cbase + c], ps);
            pd = fmaf(acc2[c], a_dst2[cbase + c], pd);
        }
#pragma unroll
        for (int m = G / 2; m >= 1; m >>= 1) {
            ps += __shfl_xor(ps, m, G);
            pd += __shfl_xor(pd, m, G);
        }
        if (valid) {
            union { unsigned int u1; uint2 u2; uint4 u4; __half2 h[C / 2]; } pk;
#pragma unroll
            for (int c = 0; c < C; c += 2)
                pk.h[c / 2] = __float22half2_rn(make_float2(acc2[c], acc2[c + 1]));
            char* dp = (char*)(Hh_out + (long)node * DOUT + cbase);
            if constexpr (C == 2) *(unsigned int*)dp = pk.u1;
            else if constexpr (C == 4) *(uint2*)dp = pk.u2;
            else                        *(uint4*)dp = pk.u4;
            if (r == 0) { ssrc2[node] = ps; sdst2[node] = pd; }
        }
    }
}

extern "C" void kernel_launch(void* const* d_in, const int* in_sizes, int n_in,
                              void* d_out, int out_size, void* d_ws, size_t ws_size,
                              hipStream_t stream) {
    const float* x  = (const float*)d_in[0];
    const int*   ei = (const int*)d_in[1];

    const float* w1  = (const float*)d_in[2];
    const float* as1 = (const float*)d_in[3];
    const float* ad1 = (const float*)d_in[4];
    const float* b1  = (const float*)d_in[5];
    const float* w2  = (const float*)d_in[6];
    const float* as2 = (const float*)d_in[7];
    const float* ad2 = (const float*)d_in[8];
    const float* b2  = (const float*)d_in[9];
    const float* w3  = (const float*)d_in[10];
    const float* as3 = (const float*)d_in[11];
    const float* ad3 = (const float*)d_in[12];
    const float* b3  = (const float*)d_in[13];
    const float* w4  = (const float*)d_in[14];
    const float* as4 = (const float*)d_in[15];
    const float* ad4 = (const float*)d_in[16];
    const float* b4  = (const float*)d_in[17];

    float* out_final = (float*)d_out;                 // [N, 64]
    float* out_h     = (float*)d_out + N_NODES * 64;  // [N, 32] (layer2 pre-relu)

    // workspace layout (float units)
    float* ws    = (float*)d_ws;
    __half* Hh_a = (__half*)ws;                 // N*64 halves
    __half* Hh_b = (__half*)(ws + N_NODES * 32);
    float* SS_a  = ws + 2 * N_NODES * 32;       // N
    float* SD_a  = SS_a + N_NODES;              // N
    float* SS_b  = SD_a + N_NODES;              // N
    float* SD_b  = SS_b + N_NODES;              // N
    int* deg     = (int*)(SD_b + N_NODES);      // N ints
    u16* bucket  = (u16*)(deg + N_NODES);       // N * BSTR u16 = 6.4MB

    const int* src = ei;                // edge_index row 0
    const int* dst = ei + N_EDGES;      // edge_index row 1

    // --- one-pass bucket CSR (scatter) || layer-1 GEMM ---
    hipMemsetAsync(deg, 0, N_NODES * sizeof(int), stream);
    scatter_gemm<<<SCAT_NB + GEMM_NB, 256, 0, stream>>>(
        src, dst, deg, bucket, x, w1, as1, ad1, Hh_a, SS_a, SD_a);

    // agg L1 (+b1, relu) -> gemm W2 -> L2 frags
    gather_gemm<64, 32><<<(N_NODES * 16 + 255) / 256, 256, 0, stream>>>(
        Hh_a, SS_a, SD_a, deg, bucket, b1, 1, nullptr,
        w2, as2, ad2, Hh_b, SS_b, SD_b);
    // agg L2 (+b2) -> out_h (pre-relu), relu -> gemm W3 -> L3 frags
    gather_gemm<32, 64><<<(N_NODES * 8 + 255) / 256, 256, 0, stream>>>(
        Hh_b, SS_b, SD_b, deg, bucket, b2, 1, out_h,
        w3, as3, ad3, Hh_a, SS_a, SD_a);
    // agg L3 (+b3, relu) -> gemm W4 -> L4 frags
    gather_gemm<64, 64><<<(N_NODES * 16 + 255) / 256, 256, 0, stream>>>(
        Hh_a, SS_a, SD_a, deg, bucket, b3, 1, nullptr,
        w4, as4, ad4, Hh_b, SS_b, SD_b);
    // agg L4 (+b4, no relu, no gemm) -> out_final
    gather_gemm<64, 0><<<(N_NODES * 16 + 255) / 256, 256, 0, stream>>>(
        Hh_b, SS_b, SD_b, deg, bucket, b4, 0, out_final,
        nullptr, nullptr, nullptr, nullptr, nullptr, nullptr);
}

// Round 15
// 257.986 us; speedup vs baseline: 1.0127x; 1.0127x over previous
//
#include <hip/hip_runtime.h>
#include <hip/hip_fp16.h>
#include <math.h>

#define N_NODES 50000
#define N_EDGES 800000
#define E_TOT   850000          // edges + self loops
#define NEG_SLOPE 0.2f
#define NB_SCAN 49              // ceil(N_NODES / 1024)
#define FILL_NB ((E_TOT + 255) / 256)     // 3321 blocks: csr_fill part
#define GEMM_NB ((N_NODES + 15) / 16)     // 3125 blocks: gemm part

typedef unsigned short u16;     // N_NODES < 65536: src ids and ranks fit in 16b
typedef float f32x4 __attribute__((ext_vector_type(4)));  // clang vector: OK for NT builtins

// ===========================================================================
// CSR-by-dst construction. deg is zeroed by hipMemsetAsync (with scan flags).
// ===========================================================================
// degree pass also records each edge's arrival rank (atomicAdd return value)
__global__ void csr_degree(const int* __restrict__ dst, int* __restrict__ deg,
                           u16* __restrict__ rank) {
    int e = blockIdx.x * blockDim.x + threadIdx.x;
    if (e >= E_TOT) return;
    int d = (e < N_EDGES) ? dst[e] : (e - N_EDGES);
    rank[e] = (u16)atomicAdd(&deg[d], 1);
}

// ---------------------------------------------------------------------------
// Single-dispatch exclusive scan via decoupled lookback. 49 blocks (all
// co-resident: grid 49 << capacity, so spinning is deadlock-free).
// aggPack[b] = (status<<32)|value; status 1=aggregate, 2=inclusive prefix.
// Packed 64-bit atomics carry value+flag together (no separate fence needed);
// aggPack is zeroed by the same memset as deg.
// ---------------------------------------------------------------------------
__global__ void scan_lookback(const int* __restrict__ deg,
                              unsigned long long* __restrict__ aggPack,
                              int* __restrict__ offs) {
    __shared__ int s[1024];
    __shared__ int bofs;
    const int bid = blockIdx.x, tid = threadIdx.x;
    const int i = bid * 1024 + tid;
    int v = (i < N_NODES) ? deg[i] : 0;
    s[tid] = v;
    __syncthreads();
    for (int off = 1; off < 1024; off <<= 1) {       // inclusive block scan
        int u = (tid >= off) ? s[tid - off] : 0;
        __syncthreads();
        s[tid] += u;
        __syncthreads();
    }
    const int agg = s[1023];
    if (tid == 0) {
        atomicExch(&aggPack[bid], (1ULL << 32) | (unsigned)agg);   // publish agg
        long long running = 0;
        for (int j = bid - 1; j >= 0; ) {
            unsigned long long p;
            do { p = atomicAdd(&aggPack[j], 0ULL); } while ((p >> 32) == 0);
            running += (unsigned)(p & 0xffffffffu);
            if ((p >> 32) == 2ULL) break;            // inclusive prefix found
            j--;
        }
        atomicExch(&aggPack[bid], (2ULL << 32) | (unsigned)(running + agg));
        bofs = (int)running;                         // exclusive block prefix
        if (bid == NB_SCAN - 1) offs[N_NODES] = (int)(running + agg);
    }
    __syncthreads();
    if (i < N_NODES) offs[i] = bofs + s[tid] - v;    // exclusive
}

// ===========================================================================
// Fused independent work: blocks [0, FILL_NB) scatter csr_src (no atomics:
// pos = offs[d] + rank[e]); blocks [FILL_NB, FILL_NB+GEMM_NB) run the
// layer-1 GEMM h = X @ W1 fused with attention projections.
// ===========================================================================
__global__ void fill_gemm(const int* __restrict__ src, const int* __restrict__ dst,
                          const u16* __restrict__ rank, const int* __restrict__ offs,
                          u16* __restrict__ csr_src,
                          const float* __restrict__ X, const float* __restrict__ W,
                          const float* __restrict__ a_src, const float* __restrict__ a_dst,
                          __half* __restrict__ Hh, float* __restrict__ ssrc,
                          float* __restrict__ sdst) {
    constexpr int DI = 64, DO = 64, TPN = DO / 4, NPB = 256 / TPN;
    if (blockIdx.x < FILL_NB) {
        int e = blockIdx.x * 256 + threadIdx.x;
        if (e >= E_TOT) return;
        int s, d;
        if (e < N_EDGES) { s = src[e]; d = dst[e]; } else { s = e - N_EDGES; d = s; }
        csr_src[offs[d] + rank[e]] = (u16)s;
        return;
    }
    // ---- gemm part ----
    __shared__ float sW[DI * DO];
    __shared__ float sX[NPB][DI + 1];          // +1: break broadcast bank aliasing
    const int tid = threadIdx.x;
    for (int i = tid; i < DI * DO / 4; i += 256)
        ((float4*)sW)[i] = ((const float4*)W)[i];
    const int base = (blockIdx.x - FILL_NB) * NPB;
    for (int i = tid; i < NPB * DI; i += 256) {
        int r = i / DI, col = i % DI;
        int node = base + r;
        sX[r][col] = (node < N_NODES) ? X[(long)node * DI + col] : 0.0f;
    }
    __syncthreads();
    const int cq = tid % TPN;
    const int g  = tid / TPN;
    const int node = base + g;
    if (node >= N_NODES) return;
    float ax = 0.0f, ay = 0.0f, az = 0.0f, aw = 0.0f;
    const float4* sW4 = (const float4*)sW;
#pragma unroll
    for (int k = 0; k < DI; k++) {
        float xv = sX[g][k];
        float4 w4 = sW4[k * TPN + cq];
        ax = fmaf(xv, w4.x, ax); ay = fmaf(xv, w4.y, ay);
        az = fmaf(xv, w4.z, az); aw = fmaf(xv, w4.w, aw);
    }
    union { uint2 u; __half2 h2[2]; } pk;
    pk.h2[0] = __float22half2_rn(make_float2(ax, ay));
    pk.h2[1] = __float22half2_rn(make_float2(az, aw));
    ((uint2*)(Hh + (long)node * DO))[cq] = pk.u;

    float4 as4 = ((const float4*)a_src)[cq];
    float4 ad4 = ((const float4*)a_dst)[cq];
    float ps = ax * as4.x + ay * as4.y + az * as4.z + aw * as4.w;
    float pd = ax * ad4.x + ay * ad4.y + az * ad4.z + aw * ad4.w;
#pragma unroll
    for (int m = TPN / 2; m >= 1; m >>= 1) {
        ps += __shfl_xor(ps, m, TPN);
        pd += __shfl_xor(pd, m, TPN);
    }
    if (cq == 0) { ssrc[node] = ps; sdst[node] = pd; }
}

// ===========================================================================
// Fused: [aggregate layer i (single-pass softmax gather) + bias (+ optional
// raw output) + relu] then [next layer's GEMM + attention projections].
// Round-5 verified body: branchless 16-deep load pipeline.
// ===========================================================================
template<int DIN, int DOUT>
__global__ void gather_gemm(const __half* __restrict__ Hh_in,
                            const float* __restrict__ ssrc_in,
                            const float* __restrict__ sdst_in,
                            const int* __restrict__ offs,
                            const u16* __restrict__ csr_src,
                            const float* __restrict__ bias_in,
                            int relu_o, float* __restrict__ extra_out,
                            const float* __restrict__ W2,
                            const float* __restrict__ a_src2,
                            const float* __restrict__ a_dst2,
                            __half* __restrict__ Hh_out,
                            float* __restrict__ ssrc2, float* __restrict__ sdst2) {
    constexpr int G = DIN / 4;                       // lanes per node group
    constexpr int L = DIN / 8;                       // lanes per row (16B each)
    constexpr int NPB = 256 / G;
    constexpr int NC = 32 / G;                       // chunks in the main path
    constexpr int JS = G / 2;                        // j-steps per chunk (2 rows/step)
    constexpr int LDSW = (DOUT > 0) ? DIN * DOUT : 1;
    __shared__ float sW[LDSW];
    if constexpr (DOUT > 0) {
        for (int i = threadIdx.x; i < DIN * DOUT / 4; i += 256)
            ((float4*)sW)[i] = ((const float4*)W2)[i];
        __syncthreads();                             // all 256 threads reach this
    }
    const int t = threadIdx.x;
    const int node = blockIdx.x * NPB + t / G;
    const int r = t % G;                             // edge slot within group
    const int hr = r / L;                            // 0/1: which edge of pair
    const int q  = r % L;                            // 16B slot within row
    const bool valid = (node < N_NODES);
    const int beg = valid ? offs[node] : 0;
    const int end = valid ? offs[node + 1] : 0;
    const int deg = end - beg;
    const float sdv = valid ? sdst_in[node] : 0.0f;
    const uint4* H4 = (const uint4*)Hh_in;

    // ---- headers for all NC main-path chunks (32 edges), issued together ----
    int   sc[NC];
    float exc[NC];
#pragma unroll
    for (int k = 0; k < NC; k++) { sc[k] = 0; exc[k] = 0.0f; }
#pragma unroll
    for (int k = 0; k < NC; k++) {
        if (k * G + r < deg) sc[k] = csr_src[beg + k * G + r];
    }
#pragma unroll
    for (int k = 0; k < NC; k++) {
        if (k * G + r < deg) {
            float v = ssrc_in[sc[k]] + sdv;
            v = (v > 0.0f) ? v : NEG_SLOPE * v;
            exc[k] = __expf(v);
        }
    }
    float den = 0.0f;
#pragma unroll
    for (int k = 0; k < NC; k++) den += exc[k];

    float acc8[8];
#pragma unroll
    for (int c = 0; c < 8; c++) acc8[c] = 0.0f;

    // ---- issue ALL 16 row-loads before any FMA (branchless, masked) ----
    uint4 buf[NC * JS];
#pragma unroll
    for (int k = 0; k < NC; k++) {
#pragma unroll
        for (int j = 0; j < JS; j++) {
            int sa = __shfl(sc[k], 2 * j + hr, G);
            buf[k * JS + j] = H4[(long)sa * L + q];
        }
    }
    // ---- consume: weighted accumulate ----
#pragma unroll
    for (int k = 0; k < NC; k++) {
#pragma unroll
        for (int j = 0; j < JS; j++) {
            float ea = __shfl(exc[k], 2 * j + hr, G);
            union { uint4 u; __half2 h2[4]; } ua;
            ua.u = buf[k * JS + j];
            float2 f0 = __half22float2(ua.h2[0]), f1 = __half22float2(ua.h2[1]);
            float2 f2 = __half22float2(ua.h2[2]), f3 = __half22float2(ua.h2[3]);
            acc8[0] = fmaf(ea, f0.x, acc8[0]); acc8[1] = fmaf(ea, f0.y, acc8[1]);
            acc8[2] = fmaf(ea, f1.x, acc8[2]); acc8[3] = fmaf(ea, f1.y, acc8[3]);
            acc8[4] = fmaf(ea, f2.x, acc8[4]); acc8[5] = fmaf(ea, f2.y, acc8[5]);
            acc8[6] = fmaf(ea, f3.x, acc8[6]); acc8[7] = fmaf(ea, f3.y, acc8[7]);
        }
    }
    // ---- rare tail chunks (deg > 32) ----
    for (int cb = beg + NC * G; cb < end; cb += G) {
        int cnt = min(G, end - cb);
        int s2 = 0; float ex2 = 0.0f;
        if (r < cnt) {
            s2 = csr_src[cb + r];
            float v = ssrc_in[s2] + sdv;
            v = (v > 0.0f) ? v : NEG_SLOPE * v;
            ex2 = __expf(v);
        }
        den += ex2;
#pragma unroll
        for (int j = 0; j < JS; j++) {
            int   sa = __shfl(s2, 2 * j + hr, G);
            float ea = __shfl(ex2, 2 * j + hr, G);
            union { uint4 u; __half2 h2[4]; } ua;
            ua.u = H4[(long)sa * L + q];
            float2 f0 = __half22float2(ua.h2[0]), f1 = __half22float2(ua.h2[1]);
            float2 f2 = __half22float2(ua.h2[2]), f3 = __half22float2(ua.h2[3]);
            acc8[0] = fmaf(ea, f0.x, acc8[0]); acc8[1] = fmaf(ea, f0.y, acc8[1]);
            acc8[2] = fmaf(ea, f1.x, acc8[2]); acc8[3] = fmaf(ea, f1.y, acc8[3]);
            acc8[4] = fmaf(ea, f2.x, acc8[4]); acc8[5] = fmaf(ea, f2.y, acc8[5]);
            acc8[6] = fmaf(ea, f3.x, acc8[6]); acc8[7] = fmaf(ea, f3.y, acc8[7]);
        }
    }
    // merge even/odd edge halves (lanes r and r^L hold same channels)
#pragma unroll
    for (int c = 0; c < 8; c++) acc8[c] += __shfl_xor(acc8[c], L, G);
#pragma unroll
    for (int m = G / 2; m >= 1; m >>= 1) den += __shfl_xor(den, m, G);

    float inv = 1.0f / (den + 1e-16f);
    const float4* b4p = (const float4*)bias_in;
    float4 bq0 = b4p[2 * q], bq1 = b4p[2 * q + 1];
    float o8[8];
    o8[0] = acc8[0] * inv + bq0.x; o8[1] = acc8[1] * inv + bq0.y;
    o8[2] = acc8[2] * inv + bq0.z; o8[3] = acc8[3] * inv + bq0.w;
    o8[4] = acc8[4] * inv + bq1.x; o8[5] = acc8[5] * inv + bq1.y;
    o8[6] = acc8[6] * inv + bq1.z; o8[7] = acc8[7] * inv + bq1.w;
    if (valid && extra_out) {
        // hr=0 lanes store even float4 slots, hr=1 odd: contiguous 2*DIN bytes
        f32x4 st;
        if (hr == 0) { st.x = o8[0]; st.y = o8[1]; st.z = o8[2]; st.w = o8[3]; }
        else         { st.x = o8[4]; st.y = o8[5]; st.z = o8[6]; st.w = o8[7]; }
        // outputs are never re-read: non-temporal keeps H resident in L2
        __builtin_nontemporal_store(st,
            &((f32x4*)extra_out)[(long)node * (2 * L) + 2 * q + hr]);  // pre-relu
    }
    if (relu_o) {
#pragma unroll
        for (int c = 0; c < 8; c++) o8[c] = fmaxf(o8[c], 0.0f);
    }

    // ---- fused next-layer GEMM + projections ----
    if constexpr (DOUT > 0) {
        constexpr int C = DOUT / G;                  // output channels per lane
        float acc2[C];
#pragma unroll
        for (int c = 0; c < C; c++) acc2[c] = 0.0f;
        const int cbase = r * C;
#pragma unroll
        for (int kb = 0; kb < L; kb++) {             // lane kb holds chans 8kb..8kb+7
            float v[8];
#pragma unroll
            for (int c8 = 0; c8 < 8; c8++) v[c8] = __shfl(o8[c8], kb, G);
#pragma unroll
            for (int c8 = 0; c8 < 8; c8++) {
                const float* wr = &sW[(8 * kb + c8) * DOUT + cbase];
#pragma unroll
                for (int c = 0; c < C; c++) acc2[c] = fmaf(v[c8], wr[c], acc2[c]);
            }
        }
        float ps = 0.0f, pd = 0.0f;
#pragma unroll
        for (int c = 0; c < C; c++) {
            ps = fmaf(acc2[c], a_src2[cbase + c], ps);
            pd = fmaf(acc2[c], a_dst2[cbase + c], pd);
        }
#pragma unroll
        for (int m = G / 2; m >= 1; m >>= 1) {
            ps += __shfl_xor(ps, m, G);
            pd += __shfl_xor(pd, m, G);
        }
        if (valid) {
            union { unsigned int u1; uint2 u2; uint4 u4; __half2 h[C / 2]; } pk;
#pragma unroll
            for (int c = 0; c < C; c += 2)
                pk.h[c / 2] = __float22half2_rn(make_float2(acc2[c], acc2[c + 1]));
            char* dp = (char*)(Hh_out + (long)node * DOUT + cbase);
            if constexpr (C == 2) *(unsigned int*)dp = pk.u1;
            else if constexpr (C == 4) *(uint2*)dp = pk.u2;
            else                        *(uint4*)dp = pk.u4;
            if (r == 0) { ssrc2[node] = ps; sdst2[node] = pd; }
        }
    }
}

extern "C" void kernel_launch(void* const* d_in, const int* in_sizes, int n_in,
                              void* d_out, int out_size, void* d_ws, size_t ws_size,
                              hipStream_t stream) {
    const float* x  = (const float*)d_in[0];
    const int*   ei = (const int*)d_in[1];

    const float* w1  = (const float*)d_in[2];
    const float* as1 = (const float*)d_in[3];
    const float* ad1 = (const float*)d_in[4];
    const float* b1  = (const float*)d_in[5];
    const float* w2  = (const float*)d_in[6];
    const float* as2 = (const float*)d_in[7];
    const float* ad2 = (const float*)d_in[8];
    const float* b2  = (const float*)d_in[9];
    const float* w3  = (const float*)d_in[10];
    const float* as3 = (const float*)d_in[11];
    const float* ad3 = (const float*)d_in[12];
    const float* b3  = (const float*)d_in[13];
    const float* w4  = (const float*)d_in[14];
    const float* as4 = (const float*)d_in[15];
    const float* ad4 = (const float*)d_in[16];
    const float* b4  = (const float*)d_in[17];

    float* out_final = (float*)d_out;                 // [N, 64]
    float* out_h     = (float*)d_out + N_NODES * 64;  // [N, 32] (layer2 pre-relu)

    // workspace layout (float units). deg and aggPack are contiguous so one
    // memset zeroes both (N*4 bytes is 8B-aligned).
    float* ws    = (float*)d_ws;
    __half* Hh_a = (__half*)ws;                 // N*64 halves
    __half* Hh_b = (__half*)(ws + N_NODES * 32);
    float* SS_a  = ws + 2 * N_NODES * 32;       // N
    float* SD_a  = SS_a + N_NODES;              // N
    float* SS_b  = SD_a + N_NODES;              // N
    float* SD_b  = SS_b + N_NODES;              // N
    int* deg     = (int*)(SD_b + N_NODES);      // N ints
    unsigned long long* aggPack = (unsigned long long*)(deg + N_NODES);  // 64 x u64
    u16* rank    = (u16*)(aggPack + 64);        // E_TOT u16 (850000 -> even count)
    int* offs    = (int*)(rank + E_TOT);        // N+1 ints
    u16* csr_src = (u16*)(offs + N_NODES + 1);  // E_TOT u16

    const int* src = ei;                // edge_index row 0
    const int* dst = ei + N_EDGES;      // edge_index row 1

    // --- build CSR by dst (once; shared by all 4 layers) ---
    hipMemsetAsync(deg, 0, N_NODES * sizeof(int) + 64 * sizeof(unsigned long long),
                   stream);                                   // deg + scan flags
    csr_degree<<<(E_TOT + 255) / 256, 256, 0, stream>>>(dst, deg, rank);
    scan_lookback<<<NB_SCAN, 1024, 0, stream>>>(deg, aggPack, offs);
    // csr_fill (blocks 0..FILL_NB) || layer-1 GEMM (blocks FILL_NB..)
    fill_gemm<<<FILL_NB + GEMM_NB, 256, 0, stream>>>(
        src, dst, rank, offs, csr_src, x, w1, as1, ad1, Hh_a, SS_a, SD_a);

    // agg L1 (+b1, relu) -> gemm W2 -> L2 frags
    gather_gemm<64, 32><<<(N_NODES * 16 + 255) / 256, 256, 0, stream>>>(
        Hh_a, SS_a, SD_a, offs, csr_src, b1, 1, nullptr,
        w2, as2, ad2, Hh_b, SS_b, SD_b);
    // agg L2 (+b2) -> out_h (pre-relu), relu -> gemm W3 -> L3 frags
    gather_gemm<32, 64><<<(N_NODES * 8 + 255) / 256, 256, 0, stream>>>(
        Hh_b, SS_b, SD_b, offs, csr_src, b2, 1, out_h,
        w3, as3, ad3, Hh_a, SS_a, SD_a);
    // agg L3 (+b3, relu) -> gemm W4 -> L4 frags
    gather_gemm<64, 64><<<(N_NODES * 16 + 255) / 256, 256, 0, stream>>>(
        Hh_a, SS_a, SD_a, offs, csr_src, b3, 1, nullptr,
        w4, as4, ad4, Hh_b, SS_b, SD_b);
    // agg L4 (+b4, no relu, no gemm) -> out_final
    gather_gemm<64, 0><<<(N_NODES * 16 + 255) / 256, 256, 0, stream>>>(
        Hh_b, SS_b, SD_b, offs, csr_src, b4, 0, out_final,
        nullptr, nullptr, nullptr, nullptr, nullptr, nullptr);
}